// Round 14
// baseline (952.656 us; speedup 1.0000x reference)
//
#include <hip/hip_runtime.h>

typedef _Float16 half8 __attribute__((ext_vector_type(8)));
typedef _Float16 half4 __attribute__((ext_vector_type(4)));
typedef float f32x4 __attribute__((ext_vector_type(4)));

// ---- ws layout (offsets in halves). All matrices have K=128 -> 4 k-chunks.
// frag layout: idx = (((nt*4 + kc)*64) + lane)*8 + j  ==  element index e itself.
constexpr int OFF_W0HI   = 0;        // 16384
constexpr int OFF_W0LO   = 16384;
constexpr int OFF_WL     = 32768;    // + m*32768 (hi), +16384 (lo), m=0..2
constexpr int OFF_WFHI   = 131072;   // 262144
constexpr int OFF_WFLO   = 393216;   // (unused by cde_kernel)
constexpr int OFF_WLASTHI = 655360;  // 8192
constexpr int OFF_WLASTLO = 663552;  // total 671744 halves = 1.31 MB

// ---- dynamic LDS layout (bytes); total 149376 <= 163840 (160 KiB)
constexpr int L_ZS   = 0;        // float [16][132]        = 8448
constexpr int L_KS   = 8448;     // float [2*16][132]      = 16896 (k1,k2 only)
constexpr int L_DX   = 25344;    // float [2][16 i][17]    = 2176  (dbuf, transposed)
constexpr int L_A0   = 27520;    // _Float16 [16][136]     = 4352  (zz/h parity 0)
constexpr int L_A1   = 31872;    // _Float16 [16][136]     = 4352  (zz/h parity 1)
constexpr int L_B    = 36224;    // _Float16 [16][136]     = 4352  (h0 ping-pong)
constexpr int L_BIAS = 40576;    // float [2624]           = 10496
constexpr int L_WFP  = 51072;    // _Float16 [8][3][4][64][8] = 98304
constexpr int LDS_BYTES = 149376;

__device__ __forceinline__ void cvt_elem(const float* __restrict__ W,
                                         _Float16* __restrict__ hi,
                                         _Float16* __restrict__ lo, int e) {
  int j  = e & 7;
  int l  = (e >> 3) & 63;
  int r  = e >> 9;
  int kc = r & 3;
  int nt = r >> 2;
  int row = nt * 16 + (l & 15);
  int col = kc * 32 + ((l >> 4) << 3) + j;
  float v = W[row * 128 + col];
  _Float16 h = (_Float16)v;
  hi[e] = h;
  lo[e] = (_Float16)(v - (float)h);
}

__global__ __launch_bounds__(256) void prep_kernel(const float* __restrict__ W0,
                                                   const float* __restrict__ Wl,
                                                   const float* __restrict__ Wf,
                                                   const float* __restrict__ Wlast,
                                                   _Float16* __restrict__ ws) {
  int e = blockIdx.x * 256 + threadIdx.x;
  if (e < 16384) {
    cvt_elem(W0, ws + OFF_W0HI, ws + OFF_W0LO, e);
  } else if (e < 65536) {
    int ee = e - 16384;
    int m = ee >> 14;
    ee &= 16383;
    cvt_elem(Wl + m * 16384, ws + OFF_WL + m * 32768,
             ws + OFF_WL + m * 32768 + 16384, ee);
  } else if (e < 327680) {
    cvt_elem(Wf, ws + OFF_WFHI, ws + OFF_WFLO, e - 65536);
  } else if (e < 335872) {
    cvt_elem(Wlast, ws + OFF_WLASTHI, ws + OFF_WLASTLO, e - 327680);
  }
}

__device__ __forceinline__ float swz_xor16(float v) {
  // ds_swizzle BitMode: xor_mask=16, and_mask=0x1F -> lane ^ 16 (per 32-half)
  return __int_as_float(__builtin_amdgcn_ds_swizzle(__float_as_int(v), 0x401F));
}

// out = sigmoid(z @ Wlast^T + b_last), swapped operands: D[m=o][n=b] so the
// 4 results per lane are consecutive o -> one coalesced f32x4 store.
__device__ __forceinline__ void out_gemm(int tt, int gb0, int w, int row, int g,
                                         const float* __restrict__ zS,
                                         const _Float16* __restrict__ ws,
                                         const float* __restrict__ biasS,
                                         float* __restrict__ out) {
  f32x4 acc = *(const f32x4*)(biasS + 2560 + w * 16 + g * 4);  // bias-init
  const int lane = g * 16 + row;
#pragma unroll
  for (int kc = 0; kc < 4; ++kc) {
    const float* zp = zS + row * 132 + kc * 32 + g * 8;
    f32x4 z0 = *(const f32x4*)zp;
    f32x4 z1 = *(const f32x4*)(zp + 4);
    half8 ah, al;
#pragma unroll
    for (int j = 0; j < 4; ++j) {
      _Float16 h = (_Float16)z0[j];
      ah[j] = h; al[j] = (_Float16)(z0[j] - (float)h);
      _Float16 h2 = (_Float16)z1[j];
      ah[4 + j] = h2; al[4 + j] = (_Float16)(z1[j] - (float)h2);
    }
    half8 bh = *(const half8*)(ws + OFF_WLASTHI + w * 2048 + (kc * 64 + lane) * 8);
    half8 bl = *(const half8*)(ws + OFF_WLASTLO + w * 2048 + (kc * 64 + lane) * 8);
    acc = __builtin_amdgcn_mfma_f32_16x16x32_f16(bh, ah, acc, 0, 0, 0);
    acc = __builtin_amdgcn_mfma_f32_16x16x32_f16(bh, al, acc, 0, 0, 0);
    acc = __builtin_amdgcn_mfma_f32_16x16x32_f16(bl, ah, acc, 0, 0, 0);
  }
  // o = w*16 + g*4 + r ; b = lane & 15
  f32x4 res;
#pragma unroll
  for (int r = 0; r < 4; ++r) {
    float e0 = __builtin_amdgcn_exp2f(-1.4426950408889634f * acc[r]);
    res[r] = __builtin_amdgcn_rcpf(1.f + e0);  // sigmoid, inf-safe
  }
  *(f32x4*)(out + ((size_t)(gb0 + row) * 32 + tt) * 64 + w * 16 + g * 4) = res;
}

__global__ __launch_bounds__(512) void cde_kernel(
    const float* __restrict__ coeffs, const float* __restrict__ W_init,
    const float* __restrict__ b_init, const float* __restrict__ b0,
    const float* __restrict__ bl, const float* __restrict__ bf,
    const float* __restrict__ b_last, const _Float16* __restrict__ ws,
    float* __restrict__ out) {
  extern __shared__ char smem[];
  float* zS    = (float*)(smem + L_ZS);
  float* kS    = (float*)(smem + L_KS);   // [2][16][132]: k1, k2
  float* dxS   = (float*)(smem + L_DX);   // [2][16*17], parity = s&1
  _Float16* bufA0 = (_Float16*)(smem + L_A0);
  _Float16* bufA1 = (_Float16*)(smem + L_A1);
  _Float16* bufB  = (_Float16*)(smem + L_B);
  float* biasS = (float*)(smem + L_BIAS);
  _Float16* wfP = (_Float16*)(smem + L_WFP);  // persist: tiles 4..6 per wave

  const int tid = threadIdx.x;
  const int w = tid >> 6;
  const int lane = tid & 63;
  const int row = lane & 15;
  const int g = lane >> 4;
  const int gb0 = blockIdx.x * 16;

  // ---- bias staging
  for (int e = tid; e < 2624; e += 512) {
    float v;
    if (e < 128)       v = b0[e];
    else if (e < 512)  v = bl[e - 128];
    else if (e < 2560) v = bf[e - 512];
    else               v = b_last[e - 2560];
    biasS[e] = v;
  }
  // ---- z0 = x0 @ W_init^T + b_init ; seed stage-0 zz buffer (parity 0)
  for (int e = tid; e < 2048; e += 512) {
    int b = e >> 7, n = e & 127;
    const float* cr = coeffs + (size_t)(gb0 + b) * (31 * 64);  // t=0, 'a' block
    float s0 = b_init[n];
#pragma unroll
    for (int i = 0; i < 16; ++i) s0 += cr[i] * W_init[n * 16 + i];
    zS[b * 132 + n] = s0;
    bufA0[b * 136 + n] = (_Float16)s0;
  }
  // ---- dx(t=0, s=0) into buffer 0 (frac = 0 -> just 'b' coefficient)
  if (tid >= 256) {
    int e = tid - 256;
    int b = e >> 4, i = e & 15;
    const float* cr = coeffs + (size_t)(gb0 + b) * 31 * 64;
    dxS[i * 17 + b] = cr[16 + i];
  }
  // ---- LDS-persist Wf tiles 4..6 per wave (96 KB, loaded ONCE)
#pragma unroll
  for (int itS = 0; itS < 3; ++itS)
#pragma unroll
    for (int kc = 0; kc < 4; ++kc) {
      half8 v = *(const half8*)(ws + OFF_WFHI + (w * 16 + 4 + itS) * 2048 +
                                (kc * 64 + lane) * 8);
      *(half8*)(wfP + (((w * 3 + itS) * 4 + kc) * 64 + lane) * 8) = v;
    }

  // ---- persistent weights: 4 hidden hi slices (64 regs) + 4 Wf tiles (64).
  // Total pinned = 128 regs (proven spill-free budget). asm-pinned.
  half8 w0h[4], w1h[4], w2h[4], w3h[4], pwf[16];
  {
#pragma unroll
    for (int kc = 0; kc < 4; ++kc) {
      w0h[kc] = *(const half8*)(ws + OFF_W0HI + w * 2048 + (kc * 64 + lane) * 8);
      w1h[kc] = *(const half8*)(ws + OFF_WL + w * 2048 + (kc * 64 + lane) * 8);
      w2h[kc] = *(const half8*)(ws + OFF_WL + 32768 + w * 2048 + (kc * 64 + lane) * 8);
      w3h[kc] = *(const half8*)(ws + OFF_WL + 65536 + w * 2048 + (kc * 64 + lane) * 8);
    }
#pragma unroll
    for (int it = 0; it < 4; ++it)
#pragma unroll
      for (int kc = 0; kc < 4; ++kc)
        pwf[it * 4 + kc] = *(const half8*)(ws + OFF_WFHI + (w * 16 + it) * 2048 +
                                           (kc * 64 + lane) * 8);
#pragma unroll
    for (int kc = 0; kc < 4; ++kc) {
      asm volatile("" : "+v"(w0h[kc]), "+v"(w1h[kc]), "+v"(w2h[kc]), "+v"(w3h[kc]));
      asm volatile("" : "+v"(pwf[kc]), "+v"(pwf[4 + kc]), "+v"(pwf[8 + kc]),
                        "+v"(pwf[12 + kc]));
    }
  }

  // Hidden layers (all hi x hi), SWAPPED operands (weights as A):
  // acc[r] = (n = w*16+g*4+r, m = row). Bias-initialized acc; 2+2 chains.
  auto hiddenHi = [&](const half8* bh, const _Float16* srcHi, _Float16* dstHi,
                      const float* bias) {
    int n0 = w * 16 + g * 4;
    f32x4 a0 = *(const f32x4*)(bias + n0);   // bias-init chain 0
    f32x4 a1 = {0.f, 0.f, 0.f, 0.f};
    half8 f0 = *(const half8*)(srcHi + row * 136 + 0 * 32 + g * 8);
    half8 f1 = *(const half8*)(srcHi + row * 136 + 1 * 32 + g * 8);
    half8 f2 = *(const half8*)(srcHi + row * 136 + 2 * 32 + g * 8);
    half8 f3 = *(const half8*)(srcHi + row * 136 + 3 * 32 + g * 8);
    a0 = __builtin_amdgcn_mfma_f32_16x16x32_f16(bh[0], f0, a0, 0, 0, 0);
    a1 = __builtin_amdgcn_mfma_f32_16x16x32_f16(bh[2], f2, a1, 0, 0, 0);
    a0 = __builtin_amdgcn_mfma_f32_16x16x32_f16(bh[1], f1, a0, 0, 0, 0);
    a1 = __builtin_amdgcn_mfma_f32_16x16x32_f16(bh[3], f3, a1, 0, 0, 0);
    f32x4 acc = a0 + a1;
    half4 hq;
#pragma unroll
    for (int r = 0; r < 4; ++r)
      hq[r] = (_Float16)fmaxf(acc[r], 0.f);
    *(half4*)(dstHi + row * 136 + n0) = hq;
  };

  __syncthreads();

  if (w < 4) out_gemm(0, gb0, w, row, g, zS, ws, biasS, out);

#pragma unroll 1
  for (int t = 0; t < 31; ++t) {
#pragma unroll 1
    for (int s = 0; s < 4; ++s) {
      // zz for this stage was produced by previous G5 (or prologue): parity s&1
      _Float16* bufP = (s & 1) ? bufA1 : bufA0;
      _Float16* bufN = (s & 1) ? bufA0 : bufA1;

      // ---- G1..G4: zero global loads (weights pinned in regs)
      hiddenHi(w0h, bufP, bufB, biasS);
      __syncthreads();
      hiddenHi(w1h, bufB, bufP, biasS + 128);
      __syncthreads();
      hiddenHi(w2h, bufP, bufB, biasS + 256);
      __syncthreads();
      hiddenHi(w3h, bufB, bufP, biasS + 384);
      __syncthreads();

      // ---- dx prefetch for NEXT stage (waves 4-7; overlaps with G5; writes
      // the alternate parity buffer, read next stage — no barrier needed)
      if (tid >= 256) {
        int sn = (s + 1) & 3;
        int tn = t + (s == 3);
        if (tn < 31) {
          int e = tid - 256;
          int b = e >> 4, i = e & 15;
          const float* cr = coeffs + ((size_t)(gb0 + b) * 31 + tn) * 64;
          float frac = (sn == 3) ? 1.f : sn * (1.f / 3.f);
          dxS[(((s & 1) ^ 1) * 272) + i * 17 + b] =
              cr[16 + i] + (cr[32 + i] + cr[48 + i] * frac) * frac;
        }
      }

      // ---- G5 (swapped): acc[r] = (i=g*4+r, b=lane&15). Reduce over i:
      // 3 adds + xor16 (ds_swizzle) + xor32 (shfl). Epilogue computes the
      // NEXT stage's zz directly (fused zz-prep: k columns consumed where
      // produced; double-buffered bufN avoids the extra barrier).
      float dxr[4], dx2[4];
#pragma unroll
      for (int r = 0; r < 4; ++r) {
        dxr[r] = dxS[(s & 1) * 272 + (g * 4 + r) * 17 + row];
        dx2[r] = dxr[r] + dxr[r];
      }
      half8 Ah[4];
#pragma unroll
      for (int kc = 0; kc < 4; ++kc)
        Ah[kc] = *(const half8*)(bufP + row * 136 + kc * 32 + g * 8);

      auto g5tile = [&](int it, const half8* bh4) {
        int nt = w * 16 + it;
        f32x4 acc = *(const f32x4*)(biasS + 512 + nt * 16 + g * 4);  // bias-init
#pragma unroll
        for (int kc = 0; kc < 4; ++kc)
          acc = __builtin_amdgcn_mfma_f32_16x16x32_f16(bh4[kc], Ah[kc], acc, 0, 0, 0);
        float tr[4];
#pragma unroll
        for (int r = 0; r < 4; ++r) {
          // tanh(x)*dx = dx - 2*dx * rcp(exp2(2*log2e*x)+1); inf-safe
          float e2 = __builtin_amdgcn_exp2f(2.8853900817779268f * acc[r]);
          float rc = __builtin_amdgcn_rcpf(e2 + 1.f);
          tr[r] = __builtin_fmaf(-dx2[r], rc, dxr[r]);
        }
        float sA = (tr[0] + tr[1]) + (tr[2] + tr[3]);  // sum over i in lane
        float sB = sA + swz_xor16(sA);                  // + lane^16
        float sC = sB + __shfl_xor(sB, 32);             // + lane^32 -> full sum
        if (lane < 16) {
          float z = zS[lane * 132 + nt];
          if (s == 0) {                                 // sC = k1
            kS[lane * 132 + nt] = sC;
            bufN[lane * 136 + nt] = (_Float16)(z + sC * (1.f / 3.f));
          } else if (s == 1) {                          // sC = k2
            float k1 = kS[lane * 132 + nt];
            kS[(16 + lane) * 132 + nt] = sC;
            bufN[lane * 136 + nt] = (_Float16)(z + sC - k1 * (1.f / 3.f));
          } else if (s == 2) {                          // sC = k3
            float k1 = kS[lane * 132 + nt];
            float k2 = kS[(16 + lane) * 132 + nt];
            zS[lane * 132 + nt] = z + 0.125f * (k1 + 3.f * (k2 + sC));
            bufN[lane * 136 + nt] = (_Float16)(z + k1 - k2 + sC);
          } else {                                      // sC = k4
            float zn = z + 0.125f * sC;
            zS[lane * 132 + nt] = zn;
            bufN[lane * 136 + nt] = (_Float16)zn;       // zz for next s=0
          }
        }
      };

      // pinned-reg tiles (it 0..3) — zero loads
#pragma unroll
      for (int it = 0; it < 4; ++it) g5tile(it, pwf + it * 4);
      // LDS-persisted tiles (it 4..6) — ds_read only, zero vmem
#pragma unroll
      for (int itS = 0; itS < 3; ++itS) {
        half8 bh4[4];
#pragma unroll
        for (int kc = 0; kc < 4; ++kc)
          bh4[kc] = *(const half8*)(wfP + (((w * 3 + itS) * 4 + kc) * 64 + lane) * 8);
        g5tile(4 + itS, bh4);
      }
      // streamed tiles (it 7..15) — running pointer, compiler-scheduled
      {
        const _Float16* bp = ws + OFF_WFHI + (w * 16 + 7) * 2048;
#pragma unroll 3
        for (int it = 7; it < 16; ++it) {
          half8 bh4[4];
#pragma unroll
          for (int kc = 0; kc < 4; ++kc)
            bh4[kc] = *(const half8*)(bp + (kc * 64 + lane) * 8);
          g5tile(it, bh4);
          bp += 2048;
        }
      }
      __syncthreads();
    }
    if (w < 4) out_gemm(t + 1, gb0, w, row, g, zS, ws, biasS, out);
  }
}

extern "C" void kernel_launch(void* const* d_in, const int* in_sizes, int n_in,
                              void* d_out, int out_size, void* d_ws, size_t ws_size,
                              hipStream_t stream) {
  const float* coeffs = (const float*)d_in[1];
  const float* W_init = (const float*)d_in[2];
  const float* b_init = (const float*)d_in[3];
  const float* W0     = (const float*)d_in[4];
  const float* b0     = (const float*)d_in[5];
  const float* Wl     = (const float*)d_in[6];
  const float* bl     = (const float*)d_in[7];
  const float* Wf     = (const float*)d_in[8];
  const float* bf     = (const float*)d_in[9];
  const float* Wlast  = (const float*)d_in[10];
  const float* b_last = (const float*)d_in[11];
  _Float16* ws = (_Float16*)d_ws;
  float* out = (float*)d_out;

  (void)hipFuncSetAttribute((const void*)cde_kernel,
                            hipFuncAttributeMaxDynamicSharedMemorySize,
                            LDS_BYTES);
  prep_kernel<<<1312, 256, 0, stream>>>(W0, Wl, Wf, Wlast, ws);
  cde_kernel<<<16, 512, LDS_BYTES, stream>>>(coeffs, W_init, b_init, b0, bl, bf,
                                             b_last, ws, out);
}

// Round 15
// 881.113 us; speedup vs baseline: 1.0812x; 1.0812x over previous
//
#include <hip/hip_runtime.h>

typedef _Float16 half8 __attribute__((ext_vector_type(8)));
typedef _Float16 half4 __attribute__((ext_vector_type(4)));
typedef float f32x4 __attribute__((ext_vector_type(4)));

// ---- ws layout (offsets in halves). All matrices have K=128 -> 4 k-chunks.
// frag layout: idx = (((nt*4 + kc)*64) + lane)*8 + j  ==  element index e itself.
constexpr int OFF_W0HI   = 0;        // 16384
constexpr int OFF_W0LO   = 16384;
constexpr int OFF_WL     = 32768;    // + m*32768 (hi), +16384 (lo), m=0..2
constexpr int OFF_WFHI   = 131072;   // 262144
constexpr int OFF_WFLO   = 393216;   // (unused by cde_kernel)
constexpr int OFF_WLASTHI = 655360;  // 8192
constexpr int OFF_WLASTLO = 663552;  // total 671744 halves = 1.31 MB

// ---- dynamic LDS layout (bytes); total 153472 <= 163840 (160 KiB)
constexpr int L_ZS   = 0;        // float [16][132]        = 8448
constexpr int L_KS   = 8448;     // float [3*16][132]      = 25344 (pad: 2-way wr)
constexpr int L_DX   = 33792;    // float [2][16 i][17]    = 2176  (dbuf, transposed)
constexpr int L_AHI  = 35968;    // _Float16 [16][136]     = 4352
constexpr int L_BHI  = 40320;    // _Float16 [16][136]     = 4352
constexpr int L_BIAS = 44672;    // float [2624]           = 10496
constexpr int L_WFP  = 55168;    // _Float16 [8][3][4][64][8] = 98304
constexpr int LDS_BYTES = 153472;

__device__ __forceinline__ void cvt_elem(const float* __restrict__ W,
                                         _Float16* __restrict__ hi,
                                         _Float16* __restrict__ lo, int e) {
  int j  = e & 7;
  int l  = (e >> 3) & 63;
  int r  = e >> 9;
  int kc = r & 3;
  int nt = r >> 2;
  int row = nt * 16 + (l & 15);
  int col = kc * 32 + ((l >> 4) << 3) + j;
  float v = W[row * 128 + col];
  _Float16 h = (_Float16)v;
  hi[e] = h;
  lo[e] = (_Float16)(v - (float)h);
}

__global__ __launch_bounds__(256) void prep_kernel(const float* __restrict__ W0,
                                                   const float* __restrict__ Wl,
                                                   const float* __restrict__ Wf,
                                                   const float* __restrict__ Wlast,
                                                   _Float16* __restrict__ ws) {
  int e = blockIdx.x * 256 + threadIdx.x;
  if (e < 16384) {
    cvt_elem(W0, ws + OFF_W0HI, ws + OFF_W0LO, e);
  } else if (e < 65536) {
    int ee = e - 16384;
    int m = ee >> 14;
    ee &= 16383;
    cvt_elem(Wl + m * 16384, ws + OFF_WL + m * 32768,
             ws + OFF_WL + m * 32768 + 16384, ee);
  } else if (e < 327680) {
    cvt_elem(Wf, ws + OFF_WFHI, ws + OFF_WFLO, e - 65536);
  } else if (e < 335872) {
    cvt_elem(Wlast, ws + OFF_WLASTHI, ws + OFF_WLASTLO, e - 327680);
  }
}

__device__ __forceinline__ float swz_xor16(float v) {
  // ds_swizzle BitMode: xor_mask=16, and_mask=0x1F -> lane ^ 16 (per 32-half)
  return __int_as_float(__builtin_amdgcn_ds_swizzle(__float_as_int(v), 0x401F));
}

// out = sigmoid(z @ Wlast^T + b_last), swapped operands: D[m=o][n=b] so the
// 4 results per lane are consecutive o -> one coalesced f32x4 store.
__device__ __forceinline__ void out_gemm(int tt, int gb0, int w, int row, int g,
                                         const float* __restrict__ zS,
                                         const _Float16* __restrict__ ws,
                                         const float* __restrict__ biasS,
                                         float* __restrict__ out) {
  f32x4 acc = *(const f32x4*)(biasS + 2560 + w * 16 + g * 4);  // bias-init
  const int lane = g * 16 + row;
#pragma unroll
  for (int kc = 0; kc < 4; ++kc) {
    const float* zp = zS + row * 132 + kc * 32 + g * 8;
    f32x4 z0 = *(const f32x4*)zp;
    f32x4 z1 = *(const f32x4*)(zp + 4);
    half8 ah, al;
#pragma unroll
    for (int j = 0; j < 4; ++j) {
      _Float16 h = (_Float16)z0[j];
      ah[j] = h; al[j] = (_Float16)(z0[j] - (float)h);
      _Float16 h2 = (_Float16)z1[j];
      ah[4 + j] = h2; al[4 + j] = (_Float16)(z1[j] - (float)h2);
    }
    half8 bh = *(const half8*)(ws + OFF_WLASTHI + w * 2048 + (kc * 64 + lane) * 8);
    half8 bl = *(const half8*)(ws + OFF_WLASTLO + w * 2048 + (kc * 64 + lane) * 8);
    acc = __builtin_amdgcn_mfma_f32_16x16x32_f16(bh, ah, acc, 0, 0, 0);
    acc = __builtin_amdgcn_mfma_f32_16x16x32_f16(bh, al, acc, 0, 0, 0);
    acc = __builtin_amdgcn_mfma_f32_16x16x32_f16(bl, ah, acc, 0, 0, 0);
  }
  // o = w*16 + g*4 + r ; b = lane & 15
  f32x4 res;
#pragma unroll
  for (int r = 0; r < 4; ++r) {
    float e0 = __builtin_amdgcn_exp2f(-1.4426950408889634f * acc[r]);
    res[r] = __builtin_amdgcn_rcpf(1.f + e0);  // sigmoid, inf-safe
  }
  *(f32x4*)(out + ((size_t)(gb0 + row) * 32 + tt) * 64 + w * 16 + g * 4) = res;
}

__global__ __launch_bounds__(512) void cde_kernel(
    const float* __restrict__ coeffs, const float* __restrict__ W_init,
    const float* __restrict__ b_init, const float* __restrict__ b0,
    const float* __restrict__ bl, const float* __restrict__ bf,
    const float* __restrict__ b_last, const _Float16* __restrict__ ws,
    float* __restrict__ out) {
  extern __shared__ char smem[];
  float* zS    = (float*)(smem + L_ZS);
  float* kS    = (float*)(smem + L_KS);
  float* dxS   = (float*)(smem + L_DX);   // [2][16*17], parity = s&1
  _Float16* bufAHi = (_Float16*)(smem + L_AHI);
  _Float16* bufBHi = (_Float16*)(smem + L_BHI);
  float* biasS = (float*)(smem + L_BIAS);
  _Float16* wfP = (_Float16*)(smem + L_WFP);  // persist: tiles 4..6 per wave

  const int tid = threadIdx.x;
  const int w = tid >> 6;
  const int lane = tid & 63;
  const int row = lane & 15;
  const int g = lane >> 4;
  const int gb0 = blockIdx.x * 16;

  // ---- bias staging
  for (int e = tid; e < 2624; e += 512) {
    float v;
    if (e < 128)       v = b0[e];
    else if (e < 512)  v = bl[e - 128];
    else if (e < 2560) v = bf[e - 512];
    else               v = b_last[e - 2560];
    biasS[e] = v;
  }
  // ---- z0 = x0 @ W_init^T + b_init
  for (int e = tid; e < 2048; e += 512) {
    int b = e >> 7, n = e & 127;
    const float* cr = coeffs + (size_t)(gb0 + b) * (31 * 64);  // t=0, 'a' block
    float s0 = b_init[n];
#pragma unroll
    for (int i = 0; i < 16; ++i) s0 += cr[i] * W_init[n * 16 + i];
    zS[b * 132 + n] = s0;
  }
  // ---- dx(t=0, s=0) into buffer 0 (frac = 0 -> just 'b' coefficient)
  if (tid >= 256) {
    int e = tid - 256;
    int b = e >> 4, i = e & 15;
    const float* cr = coeffs + (size_t)(gb0 + b) * 31 * 64;
    dxS[i * 17 + b] = cr[16 + i];
  }
  // ---- LDS-persist Wf tiles 4..6 per wave (96 KB, loaded ONCE)
#pragma unroll
  for (int itS = 0; itS < 3; ++itS)
#pragma unroll
    for (int kc = 0; kc < 4; ++kc) {
      half8 v = *(const half8*)(ws + OFF_WFHI + (w * 16 + 4 + itS) * 2048 +
                                (kc * 64 + lane) * 8);
      *(half8*)(wfP + (((w * 3 + itS) * 4 + kc) * 64 + lane) * 8) = v;
    }

  // ---- persistent weights: 4 hidden hi slices (64 regs) + 4 Wf tiles (64).
  // Total pinned = 128 regs (proven spill-free budget). asm-pinned.
  half8 w0h[4], w1h[4], w2h[4], w3h[4], pwf[16];
  {
#pragma unroll
    for (int kc = 0; kc < 4; ++kc) {
      w0h[kc] = *(const half8*)(ws + OFF_W0HI + w * 2048 + (kc * 64 + lane) * 8);
      w1h[kc] = *(const half8*)(ws + OFF_WL + w * 2048 + (kc * 64 + lane) * 8);
      w2h[kc] = *(const half8*)(ws + OFF_WL + 32768 + w * 2048 + (kc * 64 + lane) * 8);
      w3h[kc] = *(const half8*)(ws + OFF_WL + 65536 + w * 2048 + (kc * 64 + lane) * 8);
    }
#pragma unroll
    for (int it = 0; it < 4; ++it)
#pragma unroll
      for (int kc = 0; kc < 4; ++kc)
        pwf[it * 4 + kc] = *(const half8*)(ws + OFF_WFHI + (w * 16 + it) * 2048 +
                                           (kc * 64 + lane) * 8);
#pragma unroll
    for (int kc = 0; kc < 4; ++kc) {
      asm volatile("" : "+v"(w0h[kc]), "+v"(w1h[kc]), "+v"(w2h[kc]), "+v"(w3h[kc]));
      asm volatile("" : "+v"(pwf[kc]), "+v"(pwf[4 + kc]), "+v"(pwf[8 + kc]),
                        "+v"(pwf[12 + kc]));
    }
  }

  // Hidden layers (all hi x hi), SWAPPED operands (weights as A):
  // acc[r] = (n = w*16+g*4+r, m = row). Bias-initialized acc; 2+2 chains.
  auto hiddenHi = [&](const half8* bh, const _Float16* srcHi, _Float16* dstHi,
                      const float* bias) {
    int n0 = w * 16 + g * 4;
    f32x4 a0 = *(const f32x4*)(bias + n0);   // bias-init chain 0
    f32x4 a1 = {0.f, 0.f, 0.f, 0.f};
    half8 f0 = *(const half8*)(srcHi + row * 136 + 0 * 32 + g * 8);
    half8 f1 = *(const half8*)(srcHi + row * 136 + 1 * 32 + g * 8);
    half8 f2 = *(const half8*)(srcHi + row * 136 + 2 * 32 + g * 8);
    half8 f3 = *(const half8*)(srcHi + row * 136 + 3 * 32 + g * 8);
    a0 = __builtin_amdgcn_mfma_f32_16x16x32_f16(bh[0], f0, a0, 0, 0, 0);
    a1 = __builtin_amdgcn_mfma_f32_16x16x32_f16(bh[2], f2, a1, 0, 0, 0);
    a0 = __builtin_amdgcn_mfma_f32_16x16x32_f16(bh[1], f1, a0, 0, 0, 0);
    a1 = __builtin_amdgcn_mfma_f32_16x16x32_f16(bh[3], f3, a1, 0, 0, 0);
    f32x4 acc = a0 + a1;
    half4 hq;
#pragma unroll
    for (int r = 0; r < 4; ++r)
      hq[r] = (_Float16)fmaxf(acc[r], 0.f);
    *(half4*)(dstHi + row * 136 + n0) = hq;
  };

  __syncthreads();

  if (w < 4) out_gemm(0, gb0, w, row, g, zS, ws, biasS, out);

#pragma unroll 1
  for (int t = 0; t < 31; ++t) {
#pragma unroll 1
    for (int s = 0; s < 4; ++s) {
      // ---- zz = stage argument (one f32x4 per thread: 16*32 = 512), hi-only
      {
        int b = tid >> 5;
        int c = (tid & 31) * 4;
        float* zp = zS + b * 132 + c;
        f32x4 z = *(const f32x4*)zp;
        f32x4 v = z;
        if (s == 1) {
          f32x4 k1 = *(const f32x4*)(kS + b * 132 + c);
          v = z + k1 * (1.f / 3.f);
        } else if (s == 2) {
          f32x4 k1 = *(const f32x4*)(kS + b * 132 + c);
          f32x4 k2 = *(const f32x4*)(kS + (16 + b) * 132 + c);
          v = z + k2 - k1 * (1.f / 3.f);
        } else if (s == 3) {
          f32x4 k1 = *(const f32x4*)(kS + b * 132 + c);
          f32x4 k2 = *(const f32x4*)(kS + (16 + b) * 132 + c);
          f32x4 k3 = *(const f32x4*)(kS + (32 + b) * 132 + c);
          v = z + k1 - k2 + k3;
          *(f32x4*)zp = z + 0.125f * (k1 + 3.f * (k2 + k3));  // + k4/8 in G5
        }
        half4 hi;
#pragma unroll
        for (int j = 0; j < 4; ++j) hi[j] = (_Float16)v[j];
        *(half4*)(bufAHi + b * 136 + c) = hi;
      }
      __syncthreads();

      // ---- G1..G4: zero global loads (weights pinned in regs)
      hiddenHi(w0h, bufAHi, bufBHi, biasS);
      __syncthreads();
      hiddenHi(w1h, bufBHi, bufAHi, biasS + 128);
      __syncthreads();
      hiddenHi(w2h, bufAHi, bufBHi, biasS + 256);
      __syncthreads();
      hiddenHi(w3h, bufBHi, bufAHi, biasS + 384);
      __syncthreads();

      // ---- dx prefetch for NEXT stage (waves 4-7; overlaps with G5; writes
      // the alternate parity buffer, read next stage — no barrier needed)
      if (tid >= 256) {
        int sn = (s + 1) & 3;
        int tn = t + (s == 3);
        if (tn < 31) {
          int e = tid - 256;
          int b = e >> 4, i = e & 15;
          const float* cr = coeffs + ((size_t)(gb0 + b) * 31 + tn) * 64;
          float frac = (sn == 3) ? 1.f : sn * (1.f / 3.f);
          dxS[(((s & 1) ^ 1) * 272) + i * 17 + b] =
              cr[16 + i] + (cr[32 + i] + cr[48 + i] * frac) * frac;
        }
      }

      // ---- G5 (swapped): acc[r] = (i=g*4+r, b=lane&15). Reduce over i:
      // 3 adds + xor16 (ds_swizzle) + xor32 (shfl) = 7 ops.
      float dxr[4], dx2[4];
#pragma unroll
      for (int r = 0; r < 4; ++r) {
        dxr[r] = dxS[(s & 1) * 272 + (g * 4 + r) * 17 + row];
        dx2[r] = dxr[r] + dxr[r];
      }
      half8 Ah[4];
#pragma unroll
      for (int kc = 0; kc < 4; ++kc)
        Ah[kc] = *(const half8*)(bufAHi + row * 136 + kc * 32 + g * 8);

      auto g5tile = [&](int it, const half8* bh4) {
        int nt = w * 16 + it;
        f32x4 acc = *(const f32x4*)(biasS + 512 + nt * 16 + g * 4);  // bias-init
#pragma unroll
        for (int kc = 0; kc < 4; ++kc)
          acc = __builtin_amdgcn_mfma_f32_16x16x32_f16(bh4[kc], Ah[kc], acc, 0, 0, 0);
        float tr[4];
#pragma unroll
        for (int r = 0; r < 4; ++r) {
          // tanh(x)*dx = dx - 2*dx * rcp(exp2(2*log2e*x)+1); inf-safe
          float e2 = __builtin_amdgcn_exp2f(2.8853900817779268f * acc[r]);
          float rc = __builtin_amdgcn_rcpf(e2 + 1.f);
          tr[r] = __builtin_fmaf(-dx2[r], rc, dxr[r]);
        }
        float sA = (tr[0] + tr[1]) + (tr[2] + tr[3]);  // sum over i in lane
        float sB = sA + swz_xor16(sA);                  // + lane^16
        float sC = sB + __shfl_xor(sB, 32);             // + lane^32 -> full sum
        if (lane < 16) {
          if (s < 3) kS[(s * 16 + lane) * 132 + nt] = sC;  // 2-way banks (pad)
          else       zS[lane * 132 + nt] += 0.125f * sC;
        }
      };

      // pinned-reg tiles (it 0..3) — zero loads
#pragma unroll
      for (int it = 0; it < 4; ++it) g5tile(it, pwf + it * 4);
      // LDS-persisted tiles (it 4..6) — ds_read only, zero vmem
#pragma unroll
      for (int itS = 0; itS < 3; ++itS) {
        half8 bh4[4];
#pragma unroll
        for (int kc = 0; kc < 4; ++kc)
          bh4[kc] = *(const half8*)(wfP + (((w * 3 + itS) * 4 + kc) * 64 + lane) * 8);
        g5tile(4 + itS, bh4);
      }
      // streamed tiles (it 7..15) — running pointer, compiler-scheduled
      {
        const _Float16* bp = ws + OFF_WFHI + (w * 16 + 7) * 2048;
#pragma unroll 3
        for (int it = 7; it < 16; ++it) {
          half8 bh4[4];
#pragma unroll
          for (int kc = 0; kc < 4; ++kc)
            bh4[kc] = *(const half8*)(bp + (kc * 64 + lane) * 8);
          g5tile(it, bh4);
          bp += 2048;
        }
      }
      __syncthreads();
    }
    if (w < 4) out_gemm(t + 1, gb0, w, row, g, zS, ws, biasS, out);
  }
}

extern "C" void kernel_launch(void* const* d_in, const int* in_sizes, int n_in,
                              void* d_out, int out_size, void* d_ws, size_t ws_size,
                              hipStream_t stream) {
  const float* coeffs = (const float*)d_in[1];
  const float* W_init = (const float*)d_in[2];
  const float* b_init = (const float*)d_in[3];
  const float* W0     = (const float*)d_in[4];
  const float* b0     = (const float*)d_in[5];
  const float* Wl     = (const float*)d_in[6];
  const float* bl     = (const float*)d_in[7];
  const float* Wf     = (const float*)d_in[8];
  const float* bf     = (const float*)d_in[9];
  const float* Wlast  = (const float*)d_in[10];
  const float* b_last = (const float*)d_in[11];
  _Float16* ws = (_Float16*)d_ws;
  float* out = (float*)d_out;

  (void)hipFuncSetAttribute((const void*)cde_kernel,
                            hipFuncAttributeMaxDynamicSharedMemorySize,
                            LDS_BYTES);
  prep_kernel<<<1312, 256, 0, stream>>>(W0, Wl, Wf, Wlast, ws);
  cde_kernel<<<16, 512, LDS_BYTES, stream>>>(coeffs, W_init, b_init, b0, bl, bf,
                                             b_last, ws, out);
}